// Round 1
// baseline (1659.808 us; speedup 1.0000x reference)
//
#include <hip/hip_runtime.h>
#include <hip/hip_bf16.h>

// SpMM scatter: one wave (64 lanes) per edge, lane = feature index.
// out[dst*128 + col_off + lane] += w * x[src*64 + lane]
__global__ __launch_bounds__(256) void spmm_atomic_kernel(
    const int* __restrict__ idx,     // [2, E] flat: first E = dst, next E = src
    const float* __restrict__ wgt,   // [E]
    const float* __restrict__ x,     // [N, 64]
    float* __restrict__ out,         // [N, 128]
    int E, int col_off) {
    const int lane   = threadIdx.x & 63;
    const int wave   = (blockIdx.x * blockDim.x + threadIdx.x) >> 6;
    const int nwaves = (gridDim.x * blockDim.x) >> 6;

    // Contiguous chunk per wave so metadata loads hit L1 across iterations.
    const int chunk = (E + nwaves - 1) / nwaves;
    int e0 = wave * chunk;
    int e1 = e0 + chunk;
    if (e1 > E) e1 = E;

    const int* __restrict__ dstp = idx;
    const int* __restrict__ srcp = idx + E;

    for (int e = e0; e < e1; ++e) {
        const int dst  = dstp[e];           // broadcast load (same addr all lanes)
        const int src  = srcp[e];
        const float w  = wgt[e];
        const float v  = w * x[src * 64 + lane];   // coalesced 256B row gather
        atomicAdd(&out[dst * 128 + col_off + lane], v);  // fire-and-forget f32 atomic
    }
}

extern "C" void kernel_launch(void* const* d_in, const int* in_sizes, int n_in,
                              void* d_out, int out_size, void* d_ws, size_t ws_size,
                              hipStream_t stream) {
    const float* x   = (const float*)d_in[0];
    const int*   ei1 = (const int*)d_in[1];
    const float* ew1 = (const float*)d_in[2];
    const int*   ei2 = (const int*)d_in[3];
    const float* ew2 = (const float*)d_in[4];

    const int E1 = in_sizes[2];   // edge_weight1 count
    const int E2 = in_sizes[4];   // edge_weight2 count

    float* out = (float*)d_out;

    // Output accumulates via atomics -> must start from zero every call.
    hipMemsetAsync(d_out, 0, (size_t)out_size * sizeof(float), stream);

    const int block = 256;
    const int grid  = 2048;   // 8192 waves: enough TLP to hide atomic/gather latency

    spmm_atomic_kernel<<<grid, block, 0, stream>>>(ei1, ew1, x, out, E1, 0);
    spmm_atomic_kernel<<<grid, block, 0, stream>>>(ei2, ew2, x, out, E2, 64);
}

// Round 2
// 1280.228 us; speedup vs baseline: 1.2965x; 1.2965x over previous
//
#include <hip/hip_runtime.h>
#include <hip/hip_bf16.h>

#define D 64
#define SCAN_CH 4096   // elements per scan block (256 threads x 16)

// ---------------- fallback: round-1 atomic kernel (known-good) ----------------
__global__ __launch_bounds__(256) void spmm_atomic_kernel(
    const int* __restrict__ idx, const float* __restrict__ wgt,
    const float* __restrict__ x, float* __restrict__ out, int E, int col_off) {
    const int lane   = threadIdx.x & 63;
    const int wave   = (blockIdx.x * blockDim.x + threadIdx.x) >> 6;
    const int nwaves = (gridDim.x * blockDim.x) >> 6;
    const int chunk = (E + nwaves - 1) / nwaves;
    int e0 = wave * chunk, e1 = min(e0 + chunk, E);
    const int* dstp = idx;
    const int* srcp = idx + E;
    for (int e = e0; e < e1; ++e) {
        const int dst = dstp[e], src = srcp[e];
        const float v = wgt[e] * x[src * D + lane];
        atomicAdd(&out[dst * 2 * D + col_off + lane], v);
    }
}

// ---------------- CSR path ----------------

// counts[hop*N + dst]++ over both edge lists
__global__ __launch_bounds__(256) void hist_kernel(
    const int* __restrict__ ei1, const int* __restrict__ ei2,
    int E1, int E2, int N, int* __restrict__ counts) {
    int e = blockIdx.x * blockDim.x + threadIdx.x;
    int total = E1 + E2;
    if (e >= total) return;
    if (e < E1) atomicAdd(&counts[ei1[e]], 1);
    else        atomicAdd(&counts[N + ei2[e - E1]], 1);
}

// per-block sums for scan
__global__ __launch_bounds__(256) void scan_reduce_kernel(
    const int* __restrict__ counts, int M, int* __restrict__ bsum) {
    __shared__ int lds[256];
    int base = blockIdx.x * SCAN_CH;
    int s = 0;
    for (int i = threadIdx.x; i < SCAN_CH; i += 256) {
        int idx = base + i;
        s += (idx < M) ? counts[idx] : 0;
    }
    lds[threadIdx.x] = s;
    __syncthreads();
    for (int off = 128; off > 0; off >>= 1) {
        if (threadIdx.x < off) lds[threadIdx.x] += lds[threadIdx.x + off];
        __syncthreads();
    }
    if (threadIdx.x == 0) bsum[blockIdx.x] = lds[0];
}

// single-block exclusive scan of block sums (nb <= 256)
__global__ __launch_bounds__(256) void scan_bsum_kernel(int* __restrict__ bsum, int nb) {
    __shared__ int lds[256];
    int t = threadIdx.x;
    int v = (t < nb) ? bsum[t] : 0;
    lds[t] = v;
    __syncthreads();
    for (int off = 1; off < 256; off <<= 1) {
        int add = (t >= off) ? lds[t - off] : 0;
        __syncthreads();
        lds[t] += add;
        __syncthreads();
    }
    if (t < nb) bsum[t] = lds[t] - v;   // exclusive offset, in place
}

// full exclusive scan: counts -> starts (and cursor copy)
__global__ __launch_bounds__(256) void scan_write_kernel(
    const int* __restrict__ counts, int M, const int* __restrict__ boff,
    int* __restrict__ starts, int* __restrict__ cursor) {
    __shared__ int lds[256];
    int tbase = blockIdx.x * SCAN_CH + threadIdx.x * 16;
    int v[16];
    int s = 0;
#pragma unroll
    for (int i = 0; i < 16; ++i) {
        int idx = tbase + i;
        v[i] = (idx < M) ? counts[idx] : 0;
        s += v[i];
    }
    lds[threadIdx.x] = s;
    __syncthreads();
    int mine = s;
    for (int off = 1; off < 256; off <<= 1) {
        int add = (threadIdx.x >= off) ? lds[threadIdx.x - off] : 0;
        __syncthreads();
        lds[threadIdx.x] += add;
        __syncthreads();
    }
    int run = boff[blockIdx.x] + lds[threadIdx.x] - mine;  // exclusive prefix
#pragma unroll
    for (int i = 0; i < 16; ++i) {
        int idx = tbase + i;
        if (idx < M) { starts[idx] = run; cursor[idx] = run; }
        run += v[i];
    }
}

// scatter (src, w) into CSR slots
__global__ __launch_bounds__(256) void scatter_kernel(
    const int* __restrict__ ei1, const float* __restrict__ ew1,
    const int* __restrict__ ei2, const float* __restrict__ ew2,
    int E1, int E2, int N, int* __restrict__ cursor, int2* __restrict__ entries) {
    int e = blockIdx.x * blockDim.x + threadIdx.x;
    int total = E1 + E2;
    if (e >= total) return;
    int row, srcn; float w;
    if (e < E1) {
        row = ei1[e];            srcn = ei1[E1 + e];  w = ew1[e];
    } else {
        int f = e - E1;
        row = N + ei2[f];        srcn = ei2[E2 + f];  w = ew2[f];
    }
    int pos = atomicAdd(&cursor[row], 1);
    entries[pos] = make_int2(srcn, __float_as_int(w));
}

// one wave per (node, hop); lane = feature; register accumulation, single store
__global__ __launch_bounds__(256) void gather_kernel(
    const int2* __restrict__ entries, const int* __restrict__ starts,
    const float* __restrict__ x, float* __restrict__ out, int N, int Etot) {
    const int lane = threadIdx.x & 63;
    const int wave = (blockIdx.x * blockDim.x + threadIdx.x) >> 6;
    const int M = 2 * N;
    if (wave >= M) return;
    const int hop = (wave >= N) ? 1 : 0;
    const int n = wave - hop * N;
    const int s = starts[wave];
    const int e = (wave == M - 1) ? Etot : starts[wave + 1];

    float acc = 0.f;
    int base = s;
    // full 64-entry chunks: lane-parallel entry load, readlane broadcast
    for (; base + 64 <= e; base += 64) {
        int2 ent = entries[base + lane];
#pragma unroll 8
        for (int k = 0; k < 64; ++k) {
            int srcn = __builtin_amdgcn_readlane(ent.x, k);
            float w  = __int_as_float(__builtin_amdgcn_readlane(ent.y, k));
            acc += w * x[srcn * D + lane];
        }
    }
    int rem = e - base;
    if (rem > 0) {
        int2 ent = (lane < rem) ? entries[base + lane] : make_int2(0, 0);
        for (int k = 0; k < rem; ++k) {
            int srcn = __builtin_amdgcn_readlane(ent.x, k);
            float w  = __int_as_float(__builtin_amdgcn_readlane(ent.y, k));
            acc += w * x[srcn * D + lane];
        }
    }
    out[n * 2 * D + hop * D + lane] = acc;
}

extern "C" void kernel_launch(void* const* d_in, const int* in_sizes, int n_in,
                              void* d_out, int out_size, void* d_ws, size_t ws_size,
                              hipStream_t stream) {
    const float* x   = (const float*)d_in[0];
    const int*   ei1 = (const int*)d_in[1];
    const float* ew1 = (const float*)d_in[2];
    const int*   ei2 = (const int*)d_in[3];
    const float* ew2 = (const float*)d_in[4];

    const int E1 = in_sizes[2];
    const int E2 = in_sizes[4];
    const int N  = in_sizes[0] / D;
    const int Etot = E1 + E2;
    const int M  = 2 * N;

    float* out = (float*)d_out;

    // ws layout: entries [Etot int2] | counts [M] | starts [M] | cursor [M] | bsum [256]
    size_t off_entries = 0;
    size_t off_counts  = off_entries + (size_t)Etot * sizeof(int2);
    size_t off_starts  = off_counts  + (size_t)M * sizeof(int);
    size_t off_cursor  = off_starts  + (size_t)M * sizeof(int);
    size_t off_bsum    = off_cursor  + (size_t)M * sizeof(int);
    size_t needed      = off_bsum + 256 * sizeof(int);

    const int nb = (M + SCAN_CH - 1) / SCAN_CH;  // scan blocks (49 for N=100K)

    if (ws_size < needed || nb > 256) {
        // fallback: atomic scatter (round-1 path, passed at 1660 us)
        hipMemsetAsync(d_out, 0, (size_t)out_size * sizeof(float), stream);
        spmm_atomic_kernel<<<2048, 256, 0, stream>>>(ei1, ew1, x, out, E1, 0);
        spmm_atomic_kernel<<<2048, 256, 0, stream>>>(ei2, ew2, x, out, E2, D);
        return;
    }

    char* ws = (char*)d_ws;
    int2* entries = (int2*)(ws + off_entries);
    int*  counts  = (int*)(ws + off_counts);
    int*  starts  = (int*)(ws + off_starts);
    int*  cursor  = (int*)(ws + off_cursor);
    int*  bsum    = (int*)(ws + off_bsum);

    hipMemsetAsync(counts, 0, (size_t)M * sizeof(int), stream);

    const int eblocks = (Etot + 255) / 256;
    hist_kernel<<<eblocks, 256, 0, stream>>>(ei1, ei2, E1, E2, N, counts);
    scan_reduce_kernel<<<nb, 256, 0, stream>>>(counts, M, bsum);
    scan_bsum_kernel<<<1, 256, 0, stream>>>(bsum, nb);
    scan_write_kernel<<<nb, 256, 0, stream>>>(counts, M, bsum, starts, cursor);
    scatter_kernel<<<eblocks, 256, 0, stream>>>(ei1, ew1, ei2, ew2, E1, E2, N,
                                                cursor, entries);
    const int gblocks = (M * 64 + 255) / 256;
    gather_kernel<<<gblocks, 256, 0, stream>>>(entries, starts, x, out, N, Etot);
}